// Round 1
// baseline (126.295 us; speedup 1.0000x reference)
//
#include <hip/hip_runtime.h>
#include <stddef.h>

// Problem: B=1, H=16, S=4096, D=64, fp32.
// out = (Q K^T) V  ==  Q (K^T V)   [no softmax -> associativity]
// Stage 1: M[h] = K[h]^T V[h]  (64x64 per head), atomically accumulated in d_ws.
// Stage 2: O[h] = Q[h] @ M[h].

#define SLEN 4096
#define DIM  64
#define NH   16

typedef float f4v __attribute__((ext_vector_type(4)));

// ---------------- Kernel A: M = K^T V (per head), chunked over S ----------------
// grid: (32 chunks, 16 heads), 256 threads. Each chunk covers 128 S-rows.
// Thread (i = t>>4, j = t&15) owns M[4i..4i+3][4j..4j+3] partial.
__global__ __launch_bounds__(256) void kvT_kernel(const float* __restrict__ K,
                                                  const float* __restrict__ V,
                                                  float* __restrict__ M) {
    const int chunk = blockIdx.x;      // 0..31, 128 rows each
    const int h     = blockIdx.y;      // 0..15
    const int t     = threadIdx.x;
    const int i     = t >> 4;          // 0..15 (d1 group)
    const int j     = t & 15;          // 0..15 (d2 group)

    __shared__ float Ks[16][64];
    __shared__ float Vs[16][64];

    const f4v* K4 = (const f4v*)(K + ((size_t)h * SLEN + (size_t)chunk * 128) * DIM);
    const f4v* V4 = (const f4v*)(V + ((size_t)h * SLEN + (size_t)chunk * 128) * DIM);

    float acc[4][4] = {{0.f, 0.f, 0.f, 0.f},
                       {0.f, 0.f, 0.f, 0.f},
                       {0.f, 0.f, 0.f, 0.f},
                       {0.f, 0.f, 0.f, 0.f}};

    for (int tile = 0; tile < 8; ++tile) {
        // stage 16 rows of K and V: thread t loads float4 (row=i, c4=j). Coalesced.
        f4v kstage = K4[(tile * 16 + i) * 16 + j];
        f4v vstage = V4[(tile * 16 + i) * 16 + j];
        __syncthreads();   // protect previous tile's reads
        *(f4v*)&Ks[i][j * 4] = kstage;
        *(f4v*)&Vs[i][j * 4] = vstage;
        __syncthreads();

        #pragma unroll
        for (int s = 0; s < 16; ++s) {
            f4v kf = *(const f4v*)&Ks[s][i * 4];   // broadcast within wave (4 addrs)
            f4v vf = *(const f4v*)&Vs[s][j * 4];   // 2-way aliasing max (free)
            #pragma unroll
            for (int a = 0; a < 4; ++a)
                #pragma unroll
                for (int b = 0; b < 4; ++b)
                    acc[a][b] = fmaf(kf[a], vf[b], acc[a][b]);
        }
    }

    float* Mh = M + (size_t)h * DIM * DIM;
    #pragma unroll
    for (int a = 0; a < 4; ++a)
        #pragma unroll
        for (int b = 0; b < 4; ++b)
            atomicAdd(&Mh[(i * 4 + a) * DIM + j * 4 + b], acc[a][b]);
}

// ---------------- Kernel B: O = Q @ M (per head) ----------------
// grid: (64 chunks of 64 Q-rows, 16 heads), 256 threads.
// Thread (i = t>>4, j = t&15) computes O[rows 4i..4i+3][cols 4j..4j+3] of its chunk.
__global__ __launch_bounds__(256) void qm_kernel(const float* __restrict__ Q,
                                                 const float* __restrict__ M,
                                                 float* __restrict__ O) {
    const int chunk = blockIdx.x;      // 0..63, 64 rows each
    const int h     = blockIdx.y;
    const int t     = threadIdx.x;
    const int i     = t >> 4;
    const int j     = t & 15;

    __shared__ float Qs[64][68];       // +4 pad: keeps 16B alignment, breaks 16-way bank conflict
    __shared__ float Ms[64][64];

    const f4v* Q4 = (const f4v*)(Q + ((size_t)h * SLEN + (size_t)chunk * 64) * DIM);
    const f4v* M4 = (const f4v*)(M + (size_t)h * DIM * DIM);

    // stage Q tile (transposed-access-friendly padded layout) and M
    #pragma unroll
    for (int it = 0; it < 4; ++it) {
        int idx = it * 256 + t;        // 0..1023 float4s
        int row = idx >> 4;
        int c4  = idx & 15;
        *(f4v*)&Qs[row][c4 * 4] = Q4[idx];
        *(f4v*)&Ms[row][c4 * 4] = M4[idx];   // linear copy, conflict-free
    }
    __syncthreads();

    float acc[4][4] = {{0.f, 0.f, 0.f, 0.f},
                       {0.f, 0.f, 0.f, 0.f},
                       {0.f, 0.f, 0.f, 0.f},
                       {0.f, 0.f, 0.f, 0.f}};

    for (int d0 = 0; d0 < DIM; d0 += 4) {
        f4v qf[4], mf[4];
        #pragma unroll
        for (int a = 0; a < 4; ++a)
            qf[a] = *(const f4v*)&Qs[i * 4 + a][d0];     // b128, 2-way max
        #pragma unroll
        for (int c = 0; c < 4; ++c)
            mf[c] = *(const f4v*)&Ms[d0 + c][j * 4];     // b128, 2-way max
        #pragma unroll
        for (int a = 0; a < 4; ++a)
            #pragma unroll
            for (int c = 0; c < 4; ++c)
                #pragma unroll
                for (int b = 0; b < 4; ++b)
                    acc[a][b] = fmaf(qf[a][c], mf[c][b], acc[a][b]);
    }

    f4v* O4 = (f4v*)O;
    #pragma unroll
    for (int a = 0; a < 4; ++a) {
        f4v res;
        res[0] = acc[a][0]; res[1] = acc[a][1]; res[2] = acc[a][2]; res[3] = acc[a][3];
        O4[((size_t)h * SLEN + (size_t)chunk * 64 + i * 4 + a) * (DIM / 4) + j] = res;
    }
}

extern "C" void kernel_launch(void* const* d_in, const int* in_sizes, int n_in,
                              void* d_out, int out_size, void* d_ws, size_t ws_size,
                              hipStream_t stream) {
    const float* q = (const float*)d_in[0];
    const float* k = (const float*)d_in[1];
    const float* v = (const float*)d_in[2];
    float* out = (float*)d_out;
    float* M   = (float*)d_ws;          // NH * 64 * 64 floats = 256 KiB

    // M accumulators must start at zero every call (ws is re-poisoned to 0xAA).
    hipMemsetAsync(M, 0, (size_t)NH * DIM * DIM * sizeof(float), stream);

    kvT_kernel<<<dim3(32, NH), 256, 0, stream>>>(k, v, M);
    qm_kernel<<<dim3(64, NH), 256, 0, stream>>>(q, M, out);
}

// Round 2
// 108.800 us; speedup vs baseline: 1.1608x; 1.1608x over previous
//
#include <hip/hip_runtime.h>
#include <stddef.h>

// Problem: B=1, H=16, S=4096, D=64, fp32.
// out = (Q K^T) V  ==  Q (K^T V)   [no softmax -> associativity]
// Stage 1: P[h][c] = K_chunk^T V_chunk  (64x64 partials, no atomics)
// Stage 2: M[h] = sum_c P[h][c]
// Stage 3: O[h] = Q[h] @ M[h]

#define SLEN 4096
#define DIM  64
#define NH   16
#define CH   32            // S-chunks for stage 1
#define RPC  (SLEN / CH)   // 128 rows per chunk

typedef float f4v __attribute__((ext_vector_type(4)));

// ---------------- Kernel A: partial M = K^T V over a 128-row chunk ----------------
// grid (32, 16), 256 threads. Thread (i=t>>4, j=t&15) owns a 4x4 tile of the 64x64 partial.
// 32-row LDS tiles, register-prefetch of tile t+1 overlaps compute of tile t.
__global__ __launch_bounds__(256) void kvT_partial(const float* __restrict__ K,
                                                   const float* __restrict__ V,
                                                   float* __restrict__ P) {
    const int c = blockIdx.x;
    const int h = blockIdx.y;
    const int t = threadIdx.x;
    const int i = t >> 4;
    const int j = t & 15;

    __shared__ float Ks[32][64];
    __shared__ float Vs[32][64];

    const f4v* K4 = (const f4v*)(K + ((size_t)h * SLEN + (size_t)c * RPC) * DIM);
    const f4v* V4 = (const f4v*)(V + ((size_t)h * SLEN + (size_t)c * RPC) * DIM);

    float acc[4][4] = {{0.f,0.f,0.f,0.f},{0.f,0.f,0.f,0.f},
                       {0.f,0.f,0.f,0.f},{0.f,0.f,0.f,0.f}};

    // staging map: idx = u*256 + t -> row = idx>>4 (0..31), c4 = idx&15
    f4v kst[2], vst[2];
    #pragma unroll
    for (int u = 0; u < 2; ++u) {
        int idx = u * 256 + t, row = idx >> 4, c4 = idx & 15;
        kst[u] = K4[row * 16 + c4];
        vst[u] = V4[row * 16 + c4];
    }

    for (int tile = 0; tile < 4; ++tile) {
        __syncthreads();               // protect previous tile's LDS reads
        #pragma unroll
        for (int u = 0; u < 2; ++u) {
            int idx = u * 256 + t, row = idx >> 4, c4 = idx & 15;
            *(f4v*)&Ks[row][c4 * 4] = kst[u];
            *(f4v*)&Vs[row][c4 * 4] = vst[u];
        }
        __syncthreads();

        if (tile < 3) {                // prefetch next tile: latency hides under compute
            #pragma unroll
            for (int u = 0; u < 2; ++u) {
                int idx = u * 256 + t, row = idx >> 4, c4 = idx & 15;
                kst[u] = K4[((tile + 1) * 32 + row) * 16 + c4];
                vst[u] = V4[((tile + 1) * 32 + row) * 16 + c4];
            }
        }

        #pragma unroll
        for (int s = 0; s < 32; ++s) {
            f4v kf = *(const f4v*)&Ks[s][i * 4];   // 4 distinct addrs/wave -> broadcast, free
            f4v vf = *(const f4v*)&Vs[s][j * 4];   // 16 distinct, 2-way bank alias -> free
            #pragma unroll
            for (int a = 0; a < 4; ++a)
                #pragma unroll
                for (int b = 0; b < 4; ++b)
                    acc[a][b] = fmaf(kf[a], vf[b], acc[a][b]);
        }
    }

    float* Pc = P + ((size_t)h * CH + c) * (DIM * DIM);
    #pragma unroll
    for (int a = 0; a < 4; ++a) {
        f4v r;
        r[0] = acc[a][0]; r[1] = acc[a][1]; r[2] = acc[a][2]; r[3] = acc[a][3];
        *(f4v*)&Pc[(i * 4 + a) * DIM + j * 4] = r;
    }
}

// ---------------- Kernel R: M[h] = sum over 32 chunk-partials ----------------
// grid (4, 16), 256 threads; each thread owns one f4 of the head's 64x64 M.
__global__ __launch_bounds__(256) void reduceM(const float* __restrict__ P,
                                               float* __restrict__ M) {
    const int q = blockIdx.x;          // quarter of the 1024 f4s
    const int h = blockIdx.y;
    const int t = threadIdx.x;
    const int off = q * 256 + t;       // f4 index within 64x64

    const f4v* Ph = (const f4v*)(P + (size_t)h * CH * DIM * DIM);
    f4v sum; sum[0] = 0.f; sum[1] = 0.f; sum[2] = 0.f; sum[3] = 0.f;
    #pragma unroll
    for (int c = 0; c < CH; ++c) {
        f4v x = Ph[(size_t)c * (DIM * DIM / 4) + off];
        sum[0] += x[0]; sum[1] += x[1]; sum[2] += x[2]; sum[3] += x[3];
    }
    ((f4v*)(M + (size_t)h * DIM * DIM))[off] = sum;
}

// ---------------- Kernel B: O = Q @ M (per head) ----------------
// grid (64, 16), 256 threads. Thread (i,j) computes a 4x4 tile of a 64x64 output chunk.
__global__ __launch_bounds__(256) void qm_kernel(const float* __restrict__ Q,
                                                 const float* __restrict__ M,
                                                 float* __restrict__ O) {
    const int chunk = blockIdx.x;
    const int h     = blockIdx.y;
    const int t     = threadIdx.x;
    const int i     = t >> 4;
    const int j     = t & 15;

    __shared__ float Qs[64][68];       // +4 pad keeps 16B alignment, breaks bank conflicts
    __shared__ float Ms[64][64];

    const f4v* Q4 = (const f4v*)(Q + ((size_t)h * SLEN + (size_t)chunk * 64) * DIM);
    const f4v* M4 = (const f4v*)(M + (size_t)h * DIM * DIM);

    #pragma unroll
    for (int it = 0; it < 4; ++it) {
        int idx = it * 256 + t;        // 0..1023 f4s
        int row = idx >> 4;
        int c4  = idx & 15;
        *(f4v*)&Qs[row][c4 * 4] = Q4[idx];
        *(f4v*)&Ms[row][c4 * 4] = M4[idx];
    }
    __syncthreads();

    float acc[4][4] = {{0.f,0.f,0.f,0.f},{0.f,0.f,0.f,0.f},
                       {0.f,0.f,0.f,0.f},{0.f,0.f,0.f,0.f}};

    for (int d0 = 0; d0 < DIM; d0 += 4) {
        f4v qf[4], mf[4];
        #pragma unroll
        for (int a = 0; a < 4; ++a)
            qf[a] = *(const f4v*)&Qs[i * 4 + a][d0];
        #pragma unroll
        for (int cc = 0; cc < 4; ++cc)
            mf[cc] = *(const f4v*)&Ms[d0 + cc][j * 4];
        #pragma unroll
        for (int a = 0; a < 4; ++a)
            #pragma unroll
            for (int cc = 0; cc < 4; ++cc)
                #pragma unroll
                for (int b = 0; b < 4; ++b)
                    acc[a][b] = fmaf(qf[a][cc], mf[cc][b], acc[a][b]);
    }

    f4v* O4 = (f4v*)O;
    #pragma unroll
    for (int a = 0; a < 4; ++a) {
        f4v res;
        res[0] = acc[a][0]; res[1] = acc[a][1]; res[2] = acc[a][2]; res[3] = acc[a][3];
        O4[((size_t)h * SLEN + (size_t)chunk * 64 + i * 4 + a) * (DIM / 4) + j] = res;
    }
}

extern "C" void kernel_launch(void* const* d_in, const int* in_sizes, int n_in,
                              void* d_out, int out_size, void* d_ws, size_t ws_size,
                              hipStream_t stream) {
    const float* q = (const float*)d_in[0];
    const float* k = (const float*)d_in[1];
    const float* v = (const float*)d_in[2];
    float* out = (float*)d_out;
    float* P = (float*)d_ws;                                   // 16*32*4096 floats = 8 MiB
    float* M = P + (size_t)NH * CH * DIM * DIM;                // 256 KiB

    kvT_partial<<<dim3(CH, NH), 256, 0, stream>>>(k, v, P);
    reduceM<<<dim3(4, NH), 256, 0, stream>>>(P, M);
    qm_kernel<<<dim3(64, NH), 256, 0, stream>>>(q, M, out);
}